// Round 2
// baseline (7775.443 us; speedup 1.0000x reference)
//
#include <hip/hip_runtime.h>
#include <hip/hip_bf16.h>
#include <math.h>

#define D_IN 56
#define H    501
#define T_STEPS 277
#define O_OUT 76
#define BATCH 256
#define HP   512    // padded K (hidden) for MFMA
#define NP   1504   // padded 3H

typedef __attribute__((ext_vector_type(8))) short s16x8;
typedef __attribute__((ext_vector_type(4))) float f32x4;

__device__ __forceinline__ short f2bf(float x) {
    union { float f; unsigned u; } v; v.f = x;
    unsigned r = (v.u + 0x7fffu + ((v.u >> 16) & 1u)) >> 16;
    return (short)r;
}
__device__ __forceinline__ float bf2f(short b) {
    union { unsigned u; float f; } v; v.u = ((unsigned)(unsigned short)b) << 16;
    return v.f;
}
__device__ __forceinline__ float sigm(float x) { return 1.f / (1.f + __expf(-x)); }
// NaN-free fast tanh: x->-inf => -1, x->+inf => 1
__device__ __forceinline__ float tanh_fast(float x) { return 1.f - 2.f / (1.f + __expf(2.f * x)); }

// ---------------------------------------------------------------------------
// Pack GRU weights into MFMA B-fragment order, gate-sliced per unit-block:
// dst tile index = (j*3 + g)*KT + ktp ; within tile: [lane][8 halves]
// slice j owns hidden units [16j, 16j+16); gate g row = g*H + u.
// KT==32: ktp 0..15 from w_ih, 16..31 from w_hh.  KT==16: w_hh only.
// ---------------------------------------------------------------------------
__global__ void k_pack_gru(const float* __restrict__ w_ih,
                           const float* __restrict__ w_hh,
                           short* __restrict__ dst, int KT) {
    int tile = blockIdx.x;
    int ktp  = tile % KT;
    int g    = (tile / KT) % 3;
    int j    = tile / (KT * 3);
    int l    = threadIdx.x;          // 0..63
    int u    = j * 16 + (l & 15);
    int row  = g * H + u;
    const float* src; int k0;
    if (KT == 32) {
        if (ktp < 16) { src = w_ih; k0 = ktp * 32; }
        else          { src = w_hh; k0 = (ktp - 16) * 32; }
    } else          { src = w_hh; k0 = ktp * 32; }
    k0 += (l >> 4) * 8;
    short* p = dst + ((size_t)tile * 64 + l) * 8;
    for (int jj = 0; jj < 8; jj++) {
        int k = k0 + jj;
        float v = 0.f;
        if (u < H && k < H) v = src[(size_t)row * H + k];
        p[jj] = f2bf(v);
    }
}

__global__ void k_pack_fc2(const float* __restrict__ w, short* __restrict__ dst) {
    int tile = blockIdx.x;           // mt*16 + kt, mt<5, kt<16
    int kt = tile % 16, mt = tile / 16;
    int l = threadIdx.x;
    int o = mt * 16 + (l & 15);
    int k0 = kt * 32 + (l >> 4) * 8;
    short* p = dst + ((size_t)tile * 64 + l) * 8;
    for (int jj = 0; jj < 8; jj++) {
        int k = k0 + jj; float v = 0.f;
        if (o < O_OUT && k < H) v = w[(size_t)o * H + k];
        p[jj] = f2bf(v);
    }
}

// ---------------------------------------------------------------------------
// fc1 + relu:  hin[b][0..63] (padded)
// ---------------------------------------------------------------------------
__global__ void k_hin(const float* __restrict__ x, const float* __restrict__ w,
                      const float* __restrict__ bias, float* __restrict__ hin) {
    int b = blockIdx.x, o = threadIdx.x;
    float acc = 0.f;
    if (o < D_IN) {
        acc = bias[o];
        for (int k = 0; k < D_IN; k++) acc += x[b * D_IN + k] * w[o * D_IN + k];
        acc = fmaxf(acc, 0.f);
    }
    hin[b * 64 + o] = (o < D_IN) ? acc : 0.f;
}

// g0[b][NP] = hin[b] @ w_ih0^T + b_ih0   (constant over t; fp32)
__global__ void k_g0(const float* __restrict__ hin, const float* __restrict__ w_ih0,
                     const float* __restrict__ b_ih0, float* __restrict__ g0) {
    int b = blockIdx.x, tid = threadIdx.x;
    __shared__ float shx[D_IN];
    if (tid < D_IN) shx[tid] = hin[b * 64 + tid];
    __syncthreads();
    for (int o = tid; o < NP; o += 256) {
        float acc = 0.f;
        if (o < 3 * H) {
            acc = b_ih0[o];
            for (int k = 0; k < D_IN; k++) acc += shx[k] * w_ih0[(size_t)o * D_IN + k];
        }
        g0[(size_t)b * NP + o] = acc;
    }
}

// ---------------------------------------------------------------------------
// Persistent pipelined GRU: 256 blocks (j 0..31 unit-slice, bg 0..7 batch
// group), 384 threads = 6 waves = (gate nt, part). Per global step s:
//   layer0 computes t=s, layer1 t=s-1, layer2 t=s-2  (wavefront pipeline)
// then a per-bg-group 32-block flag barrier. Weights live in VGPRs (160/lane)
// for the whole kernel so post-barrier L2 invalidations never touch them.
// Layer0 has no per-step x-gates (g0 constant): its 16 hh k-tiles are split
// 8/8 across part0/part1; gate math sums the two partials.
// ysA is written by layer0 at t and safely overwritten by layer2 at t (step
// t+2), after layer1 consumed it (step t+1) — barriers order all of it.
// ---------------------------------------------------------------------------
__global__ __launch_bounds__(384, 2)
void k_gru_persist(const short* __restrict__ packW0,
                   const short* __restrict__ packW1,
                   const short* __restrict__ packW2,
                   const float* __restrict__ g0,
                   const float* __restrict__ b_hh0,
                   const float* __restrict__ b_ih1, const float* __restrict__ b_hh1,
                   const float* __restrict__ b_ih2, const float* __restrict__ b_hh2,
                   short* __restrict__ hbuf,   // [3 layers][2 parity][BATCH][HP]
                   short* __restrict__ ysA,    // layer0 out, reused as layer2 out
                   short* __restrict__ ysB,    // layer1 out
                   unsigned* __restrict__ flags) {
    const int j    = blockIdx.x & 31;
    const int bg   = blockIdx.x >> 5;
    const int b0   = bg * 32;
    const int tid  = threadIdx.x;
    const int lane = tid & 63;
    const int wave = tid >> 6;
    const int nt   = wave >> 1;        // gate 0..2
    const int part = wave & 1;
    const int arow = lane & 15;
    const int acol = (lane >> 4) * 8;

    __shared__ __align__(16) short sh[32 * 520];   // h rows staging (33,280 B)
    __shared__ float hg[6][544];                   // MFMA results (13,056 B)
    __shared__ float sg0[32 * 48];                 // layer0 x-gates (6,144 B)
    __shared__ float sb[3][4][16];                 // biases (768 B)

    // ---- preload weight fragments into registers (persist across t-loop)
    s16x8 w0f[8], w1f[16], w2f[16];
    {
        const short* p0 = packW0 + ((size_t)((j * 3 + nt) * 16 + part * 8) * 64) * 8;
        #pragma unroll
        for (int i = 0; i < 8; i++)  w0f[i] = *(const s16x8*)&p0[((size_t)i * 64 + lane) * 8];
        const short* p1 = packW1 + ((size_t)((j * 3 + nt) * 32 + part * 16) * 64) * 8;
        #pragma unroll
        for (int i = 0; i < 16; i++) w1f[i] = *(const s16x8*)&p1[((size_t)i * 64 + lane) * 8];
        const short* p2 = packW2 + ((size_t)((j * 3 + nt) * 32 + part * 16) * 64) * 8;
        #pragma unroll
        for (int i = 0; i < 16; i++) w2f[i] = *(const s16x8*)&p2[((size_t)i * 64 + lane) * 8];
    }
    // ---- layer0 x-gate constants (g0 + b_hh0 folded for r,z)
    for (int c = tid; c < 32 * 48; c += 384) {
        int m = c / 48, col = c % 48;
        int g = col >> 4, ul = col & 15;
        int u = j * 16 + ul;
        float v = 0.f;
        if (u < H) {
            v = g0[(size_t)(b0 + m) * NP + g * H + u];
            if (g == 0) v += b_hh0[u];
            else if (g == 1) v += b_hh0[H + u];
        }
        sg0[m * 48 + col] = v;
    }
    // ---- per-layer biases
    if (tid < 48) {
        int l = tid >> 4, ul = tid & 15, u = j * 16 + ul;
        float br = 0.f, bz = 0.f, bxn = 0.f, bhn = 0.f;
        if (u < H) {
            if (l == 0) bhn = b_hh0[2 * H + u];
            else {
                const float* bi = (l == 1) ? b_ih1 : b_ih2;
                const float* bh = (l == 1) ? b_hh1 : b_hh2;
                br = bi[u] + bh[u]; bz = bi[H + u] + bh[H + u];
                bxn = bi[2 * H + u]; bhn = bh[2 * H + u];
            }
        }
        sb[l][0][ul] = br; sb[l][1][ul] = bz; sb[l][2][ul] = bxn; sb[l][3][ul] = bhn;
    }
    __syncthreads();

    short* hb0 = hbuf;
    short* hb1 = hbuf + (size_t)2 * BATCH * HP;
    short* hb2 = hbuf + (size_t)4 * BATCH * HP;
    unsigned* gflag = flags + bg * 32;

    auto stage = [&](const short* hb, int t) {
        const short* src = hb + (size_t)((t & 1) ^ 1) * BATCH * HP;
        const s16x8 z8 = {0, 0, 0, 0, 0, 0, 0, 0};
        for (int c = tid; c < 2048; c += 384) {
            int r = c >> 6, cc = c & 63;
            s16x8 v = z8;
            if (t != 0) v = *(const s16x8*)&src[(size_t)(b0 + r) * HP + cc * 8];
            *(s16x8*)&sh[r * 520 + cc * 8] = v;
        }
    };
    auto put_hg = [&](const f32x4& a0, const f32x4& a1) {
        float* d = hg[nt * 2 + part];
        int ul = lane & 15, mrow = (lane >> 4) * 4;
        #pragma unroll
        for (int r = 0; r < 4; r++) {
            d[(mrow + r) * 17 + ul]      = a0[r];
            d[(16 + mrow + r) * 17 + ul] = a1[r];
        }
    };
    auto gate0 = [&](int t) {
        short* hdst = hb0 + (size_t)(t & 1) * BATCH * HP;
        for (int idx = tid; idx < 512; idx += 384) {
            int m = idx >> 4, ul = idx & 15;
            int b = b0 + m, u = j * 16 + ul;
            int mo = m * 17 + ul;
            float hr = hg[0][mo] + hg[1][mo];
            float hz = hg[2][mo] + hg[3][mo];
            float hn = hg[4][mo] + hg[5][mo];
            float r = sigm(sg0[m * 48 + ul] + hr);
            float z = sigm(sg0[m * 48 + 16 + ul] + hz);
            float n = tanh_fast(sg0[m * 48 + 32 + ul] + r * (hn + sb[0][3][ul]));
            float hold = bf2f(sh[m * 520 + u]);
            float hnew = (1.f - z) * n + z * hold;
            short hv = (u < H) ? f2bf(hnew) : (short)0;
            hdst[(size_t)b * HP + u] = hv;
            ysA[((size_t)t * BATCH + b) * HP + u] = hv;
        }
    };
    auto gate12 = [&](int l, int t, short* hb, short* ys) {
        short* hdst = hb + (size_t)(t & 1) * BATCH * HP;
        for (int idx = tid; idx < 512; idx += 384) {
            int m = idx >> 4, ul = idx & 15;
            int b = b0 + m, u = j * 16 + ul;
            int mo = m * 17 + ul;
            float xr = hg[0][mo] + sb[l][0][ul];
            float hr = hg[1][mo];
            float xz = hg[2][mo] + sb[l][1][ul];
            float hz = hg[3][mo];
            float xn = hg[4][mo] + sb[l][2][ul];
            float hn = hg[5][mo] + sb[l][3][ul];
            float r = sigm(xr + hr);
            float z = sigm(xz + hz);
            float n = tanh_fast(xn + r * hn);
            float hold = bf2f(sh[m * 520 + u]);
            float hnew = (1.f - z) * n + z * hold;
            short hv = (u < H) ? f2bf(hnew) : (short)0;
            hdst[(size_t)b * HP + u] = hv;
            ys[((size_t)t * BATCH + b) * HP + u] = hv;
        }
    };

    for (int s = 0; s < T_STEPS + 2; ++s) {
        // ---------------- layer 0: t = s
        if (s < T_STEPS) {
            int t = s;
            stage(hb0, t);
            __syncthreads();
            f32x4 a0 = {0.f, 0.f, 0.f, 0.f}, a1 = {0.f, 0.f, 0.f, 0.f};
            #pragma unroll
            for (int i = 0; i < 8; i++) {
                int kk = part * 8 + i;
                s16x8 x0 = *(const s16x8*)&sh[arow * 520 + kk * 32 + acol];
                s16x8 x1 = *(const s16x8*)&sh[(16 + arow) * 520 + kk * 32 + acol];
                a0 = __builtin_amdgcn_mfma_f32_16x16x32_bf16(x0, w0f[i], a0, 0, 0, 0);
                a1 = __builtin_amdgcn_mfma_f32_16x16x32_bf16(x1, w0f[i], a1, 0, 0, 0);
            }
            put_hg(a0, a1);
            __syncthreads();
            gate0(t);
            __syncthreads();
        }
        // ---------------- layer 1: t = s-1, x = ysA[t]
        if (s >= 1 && s <= T_STEPS) {
            int t = s - 1;
            stage(hb1, t);
            __syncthreads();
            f32x4 a0 = {0.f, 0.f, 0.f, 0.f}, a1 = {0.f, 0.f, 0.f, 0.f};
            if (part == 0) {
                const short* xs = ysA + (size_t)t * BATCH * HP;
                #pragma unroll
                for (int kk = 0; kk < 16; kk++) {
                    s16x8 x0 = *(const s16x8*)&xs[(size_t)(b0 + arow) * HP + kk * 32 + acol];
                    s16x8 x1 = *(const s16x8*)&xs[(size_t)(b0 + 16 + arow) * HP + kk * 32 + acol];
                    a0 = __builtin_amdgcn_mfma_f32_16x16x32_bf16(x0, w1f[kk], a0, 0, 0, 0);
                    a1 = __builtin_amdgcn_mfma_f32_16x16x32_bf16(x1, w1f[kk], a1, 0, 0, 0);
                }
            } else {
                #pragma unroll
                for (int kk = 0; kk < 16; kk++) {
                    s16x8 x0 = *(const s16x8*)&sh[arow * 520 + kk * 32 + acol];
                    s16x8 x1 = *(const s16x8*)&sh[(16 + arow) * 520 + kk * 32 + acol];
                    a0 = __builtin_amdgcn_mfma_f32_16x16x32_bf16(x0, w1f[kk], a0, 0, 0, 0);
                    a1 = __builtin_amdgcn_mfma_f32_16x16x32_bf16(x1, w1f[kk], a1, 0, 0, 0);
                }
            }
            put_hg(a0, a1);
            __syncthreads();
            gate12(1, t, hb1, ysB);
            __syncthreads();
        }
        // ---------------- layer 2: t = s-2, x = ysB[t], out -> ysA[t] (reuse)
        if (s >= 2) {
            int t = s - 2;
            stage(hb2, t);
            __syncthreads();
            f32x4 a0 = {0.f, 0.f, 0.f, 0.f}, a1 = {0.f, 0.f, 0.f, 0.f};
            if (part == 0) {
                const short* xs = ysB + (size_t)t * BATCH * HP;
                #pragma unroll
                for (int kk = 0; kk < 16; kk++) {
                    s16x8 x0 = *(const s16x8*)&xs[(size_t)(b0 + arow) * HP + kk * 32 + acol];
                    s16x8 x1 = *(const s16x8*)&xs[(size_t)(b0 + 16 + arow) * HP + kk * 32 + acol];
                    a0 = __builtin_amdgcn_mfma_f32_16x16x32_bf16(x0, w2f[kk], a0, 0, 0, 0);
                    a1 = __builtin_amdgcn_mfma_f32_16x16x32_bf16(x1, w2f[kk], a1, 0, 0, 0);
                }
            } else {
                #pragma unroll
                for (int kk = 0; kk < 16; kk++) {
                    s16x8 x0 = *(const s16x8*)&sh[arow * 520 + kk * 32 + acol];
                    s16x8 x1 = *(const s16x8*)&sh[(16 + arow) * 520 + kk * 32 + acol];
                    a0 = __builtin_amdgcn_mfma_f32_16x16x32_bf16(x0, w2f[kk], a0, 0, 0, 0);
                    a1 = __builtin_amdgcn_mfma_f32_16x16x32_bf16(x1, w2f[kk], a1, 0, 0, 0);
                }
            }
            put_hg(a0, a1);
            __syncthreads();
            gate12(2, t, hb2, ysA);
            __syncthreads();
        }
        // ---------------- per-bg-group barrier (32 blocks)
        __syncthreads();
        if (tid == 0) {
            __threadfence();   // release: drain + L2 writeback (agent scope)
            __hip_atomic_store(&gflag[j], (unsigned)(s + 1),
                               __ATOMIC_RELAXED, __HIP_MEMORY_SCOPE_AGENT);
        }
        if (tid < 32) {
            while (__hip_atomic_load(&gflag[tid], __ATOMIC_RELAXED,
                                     __HIP_MEMORY_SCOPE_AGENT) < (unsigned)(s + 1)) {}
        }
        if (wave == 0) __threadfence();  // acquire: invalidate L1/L2
        __syncthreads();
    }
}

// ---------------------------------------------------------------------------
// fc2 + transpose: out[b][o][t] = ys2[t][b][:] . fc2_w[o][:] + fc2_b[o]
// ---------------------------------------------------------------------------
__global__ __launch_bounds__(256, 1)
void k_fc2(const short* __restrict__ ys2, const short* __restrict__ fc2p,
           const float* __restrict__ fc2_b, float* __restrict__ out) {
    int b = blockIdx.x;
    int tid = threadIdx.x, lane = tid & 63, wave = tid >> 6;
    const s16x8 zf = {0, 0, 0, 0, 0, 0, 0, 0};
    for (int ntile = wave; ntile < 18; ntile += 4) {
        int tt = ntile * 16 + (lane & 15);
        s16x8 bf[16];
        for (int kt = 0; kt < 16; kt++) {
            if (tt < T_STEPS)
                bf[kt] = *(const s16x8*)&ys2[((size_t)tt * BATCH + b) * HP + kt * 32 + (lane >> 4) * 8];
            else
                bf[kt] = zf;
        }
        for (int mt = 0; mt < 5; mt++) {
            f32x4 acc = {0.f, 0.f, 0.f, 0.f};
            for (int kt = 0; kt < 16; kt++) {
                s16x8 af = *(const s16x8*)&fc2p[(((size_t)mt * 16 + kt) * 64 + lane) * 8];
                acc = __builtin_amdgcn_mfma_f32_16x16x32_bf16(af, bf[kt], acc, 0, 0, 0);
            }
            int obase = mt * 16 + (lane >> 4) * 4;
            for (int r = 0; r < 4; r++) {
                int o = obase + r;
                if (o < O_OUT && tt < T_STEPS)
                    out[((size_t)b * O_OUT + o) * T_STEPS + tt] = acc[r] + fc2_b[o];
            }
        }
    }
}

// ---------------------------------------------------------------------------
extern "C" void kernel_launch(void* const* d_in, const int* in_sizes, int n_in,
                              void* d_out, int out_size, void* d_ws, size_t ws_size,
                              hipStream_t stream) {
    const float* x     = (const float*)d_in[0];
    const float* fc1_w = (const float*)d_in[1];
    const float* fc1_b = (const float*)d_in[2];
    const float* w_ih0 = (const float*)d_in[3];
    const float* w_hh0 = (const float*)d_in[4];
    const float* b_ih0 = (const float*)d_in[5];
    const float* b_hh0 = (const float*)d_in[6];
    const float* w_ih1 = (const float*)d_in[7];
    const float* w_hh1 = (const float*)d_in[8];
    const float* b_ih1 = (const float*)d_in[9];
    const float* b_hh1 = (const float*)d_in[10];
    const float* w_ih2 = (const float*)d_in[11];
    const float* w_hh2 = (const float*)d_in[12];
    const float* b_ih2 = (const float*)d_in[13];
    const float* b_hh2 = (const float*)d_in[14];
    const float* fc2_w = (const float*)d_in[15];
    const float* fc2_b = (const float*)d_in[16];
    float* out = (float*)d_out;

    char* p = (char*)d_ws;
    auto alloc = [&](size_t bytes) {
        char* r = p; p += (bytes + 255) & ~(size_t)255; return r;
    };
    short* packW0 = (short*)alloc((size_t)32 * 3 * 16 * 64 * 8 * 2);
    short* packW1 = (short*)alloc((size_t)32 * 3 * 32 * 64 * 8 * 2);
    short* packW2 = (short*)alloc((size_t)32 * 3 * 32 * 64 * 8 * 2);
    short* packF  = (short*)alloc((size_t)80 * 64 * 8 * 2);
    float* hin    = (float*)alloc((size_t)BATCH * 64 * 4);
    float* g0     = (float*)alloc((size_t)BATCH * NP * 4);
    short* hbuf   = (short*)alloc((size_t)3 * 2 * BATCH * HP * 2);
    unsigned* flags = (unsigned*)alloc(256 * 4);
    short* ysA    = (short*)alloc((size_t)T_STEPS * BATCH * HP * 2);
    short* ysB    = (short*)alloc((size_t)T_STEPS * BATCH * HP * 2);

    hipMemsetAsync(flags, 0, 256 * 4, stream);
    k_pack_gru<<<32 * 3 * 16, 64, 0, stream>>>(nullptr, w_hh0, packW0, 16);
    k_pack_gru<<<32 * 3 * 32, 64, 0, stream>>>(w_ih1, w_hh1, packW1, 32);
    k_pack_gru<<<32 * 3 * 32, 64, 0, stream>>>(w_ih2, w_hh2, packW2, 32);
    k_pack_fc2<<<80, 64, 0, stream>>>(fc2_w, packF);
    k_hin<<<BATCH, 64, 0, stream>>>(x, fc1_w, fc1_b, hin);
    k_g0<<<BATCH, 256, 0, stream>>>(hin, w_ih0, b_ih0, g0);

    k_gru_persist<<<256, 384, 0, stream>>>(packW0, packW1, packW2, g0,
                                           b_hh0, b_ih1, b_hh1, b_ih2, b_hh2,
                                           hbuf, ysA, ysB, flags);

    k_fc2<<<BATCH, 256, 0, stream>>>(ysA, packF, fc2_b, out);
}

// Round 3
// 3635.263 us; speedup vs baseline: 2.1389x; 2.1389x over previous
//
#include <hip/hip_runtime.h>
#include <hip/hip_bf16.h>
#include <math.h>

#define D_IN 56
#define H    501
#define T_STEPS 277
#define O_OUT 76
#define BATCH 256
#define HP   512    // padded K (hidden) for MFMA
#define NP   1504   // padded 3H

typedef __attribute__((ext_vector_type(8))) short s16x8;
typedef __attribute__((ext_vector_type(4))) float f32x4;
typedef unsigned long long ull;

__device__ __forceinline__ short f2bf(float x) {
    union { float f; unsigned u; } v; v.f = x;
    unsigned r = (v.u + 0x7fffu + ((v.u >> 16) & 1u)) >> 16;
    return (short)r;
}
__device__ __forceinline__ float bf2f(short b) {
    union { unsigned u; float f; } v; v.u = ((unsigned)(unsigned short)b) << 16;
    return v.f;
}
__device__ __forceinline__ float sigm(float x) { return 1.f / (1.f + __expf(-x)); }
__device__ __forceinline__ float tanh_fast(float x) { return 1.f - 2.f / (1.f + __expf(2.f * x)); }

// ---------------------------------------------------------------------------
// Weight packing (unchanged from R2, proven correct)
// ---------------------------------------------------------------------------
__global__ void k_pack_gru(const float* __restrict__ w_ih,
                           const float* __restrict__ w_hh,
                           short* __restrict__ dst, int KT) {
    int tile = blockIdx.x;
    int ktp  = tile % KT;
    int g    = (tile / KT) % 3;
    int j    = tile / (KT * 3);
    int l    = threadIdx.x;
    int u    = j * 16 + (l & 15);
    int row  = g * H + u;
    const float* src; int k0;
    if (KT == 32) {
        if (ktp < 16) { src = w_ih; k0 = ktp * 32; }
        else          { src = w_hh; k0 = (ktp - 16) * 32; }
    } else          { src = w_hh; k0 = ktp * 32; }
    k0 += (l >> 4) * 8;
    short* p = dst + ((size_t)tile * 64 + l) * 8;
    for (int jj = 0; jj < 8; jj++) {
        int k = k0 + jj;
        float v = 0.f;
        if (u < H && k < H) v = src[(size_t)row * H + k];
        p[jj] = f2bf(v);
    }
}

__global__ void k_pack_fc2(const float* __restrict__ w, short* __restrict__ dst) {
    int tile = blockIdx.x;
    int kt = tile % 16, mt = tile / 16;
    int l = threadIdx.x;
    int o = mt * 16 + (l & 15);
    int k0 = kt * 32 + (l >> 4) * 8;
    short* p = dst + ((size_t)tile * 64 + l) * 8;
    for (int jj = 0; jj < 8; jj++) {
        int k = k0 + jj; float v = 0.f;
        if (o < O_OUT && k < H) v = w[(size_t)o * H + k];
        p[jj] = f2bf(v);
    }
}

__global__ void k_hin(const float* __restrict__ x, const float* __restrict__ w,
                      const float* __restrict__ bias, float* __restrict__ hin) {
    int b = blockIdx.x, o = threadIdx.x;
    float acc = 0.f;
    if (o < D_IN) {
        acc = bias[o];
        for (int k = 0; k < D_IN; k++) acc += x[b * D_IN + k] * w[o * D_IN + k];
        acc = fmaxf(acc, 0.f);
    }
    hin[b * 64 + o] = (o < D_IN) ? acc : 0.f;
}

__global__ void k_g0(const float* __restrict__ hin, const float* __restrict__ w_ih0,
                     const float* __restrict__ b_ih0, float* __restrict__ g0) {
    int b = blockIdx.x, tid = threadIdx.x;
    __shared__ float shx[D_IN];
    if (tid < D_IN) shx[tid] = hin[b * 64 + tid];
    __syncthreads();
    for (int o = tid; o < NP; o += 256) {
        float acc = 0.f;
        if (o < 3 * H) {
            acc = b_ih0[o];
            for (int k = 0; k < D_IN; k++) acc += shx[k] * w_ih0[(size_t)o * D_IN + k];
        }
        g0[(size_t)b * NP + o] = acc;
    }
}

// ---------------------------------------------------------------------------
// Persistent pipelined GRU with epoch-addressed fence-free exchange.
// grid 256 = (j 0..31 unit-slice) x (bg 0..7 batch group of 32 rows);
// bg = blockIdx&7 so a barrier group maps to one XCD (perf heuristic only).
// Writers: sc1 bypass stores (relaxed agent atomics). Readers: cached loads
// for addresses never previously touched by the XCD this call (fresh L2 miss
// => L3 => correct); bypass loads only for l2-h (ysA[s-3], re-written lines).
// Barrier: per-bg counter, release fetch_add + relaxed poll (no invalidate).
// ---------------------------------------------------------------------------
__global__ __launch_bounds__(384, 1)
void k_gru_persist(const short* __restrict__ packW0,
                   const short* __restrict__ packW1,
                   const short* __restrict__ packW2,
                   const float* __restrict__ g0,
                   const float* __restrict__ b_hh0,
                   const float* __restrict__ b_ih1, const float* __restrict__ b_hh1,
                   const float* __restrict__ b_ih2, const float* __restrict__ b_hh2,
                   short* __restrict__ ysA,    // layer0 out at t, overwritten by layer2 at t (step t+2)
                   short* __restrict__ ysB,    // layer1 out
                   unsigned* __restrict__ cnt) {
    const int bg   = blockIdx.x & 7;
    const int j    = blockIdx.x >> 3;
    const int b0   = bg * 32;
    const int tid  = threadIdx.x;
    const int lane = tid & 63;
    const int wave = tid >> 6;
    const int nt   = wave >> 1;        // gate 0..2
    const int part = wave & 1;
    const int arow = lane & 15;
    const int acol = (lane >> 4) * 8;
    const s16x8 z8 = {0, 0, 0, 0, 0, 0, 0, 0};

    __shared__ __align__(16) short sh[32 * 520];   // one staging buffer (33,280 B)
    __shared__ float hg[6][544];                   // MFMA results (13,056 B)
    __shared__ float sg0[32 * 48];                 // layer0 x-gates (6,144 B)
    __shared__ float sb[3][4][16];                 // folded biases

    // ---- weight fragments -> VGPRs, pinned for the whole kernel
    s16x8 w0f[8], w1f[16], w2f[16];
    {
        const short* p0 = packW0 + ((size_t)((j * 3 + nt) * 16 + part * 8) * 64) * 8;
        #pragma unroll
        for (int i = 0; i < 8; i++)  w0f[i] = *(const s16x8*)&p0[((size_t)i * 64 + lane) * 8];
        const short* p1 = packW1 + ((size_t)((j * 3 + nt) * 32 + part * 16) * 64) * 8;
        #pragma unroll
        for (int i = 0; i < 16; i++) w1f[i] = *(const s16x8*)&p1[((size_t)i * 64 + lane) * 8];
        const short* p2 = packW2 + ((size_t)((j * 3 + nt) * 32 + part * 16) * 64) * 8;
        #pragma unroll
        for (int i = 0; i < 16; i++) w2f[i] = *(const s16x8*)&p2[((size_t)i * 64 + lane) * 8];
        #pragma unroll
        for (int i = 0; i < 8; i++)  asm volatile("" : "+v"(w0f[i]));
        #pragma unroll
        for (int i = 0; i < 16; i++) asm volatile("" : "+v"(w1f[i]));
        #pragma unroll
        for (int i = 0; i < 16; i++) asm volatile("" : "+v"(w2f[i]));
    }
    // ---- layer0 x-gate constants (g0 + b_hh0 folded for r,z)
    for (int c = tid; c < 32 * 48; c += 384) {
        int m = c / 48, col = c % 48;
        int g = col >> 4, ul = col & 15;
        int u = j * 16 + ul;
        float v = 0.f;
        if (u < H) {
            v = g0[(size_t)(b0 + m) * NP + g * H + u];
            if (g == 0) v += b_hh0[u];
            else if (g == 1) v += b_hh0[H + u];
        }
        sg0[m * 48 + col] = v;
    }
    if (tid < 48) {
        int l = tid >> 4, ul = tid & 15, u = j * 16 + ul;
        float br = 0.f, bz = 0.f, bxn = 0.f, bhn = 0.f;
        if (u < H) {
            if (l == 0) bhn = b_hh0[2 * H + u];
            else {
                const float* bi = (l == 1) ? b_ih1 : b_ih2;
                const float* bh = (l == 1) ? b_hh1 : b_hh2;
                br = bi[u] + bh[u]; bz = bi[H + u] + bh[H + u];
                bxn = bi[2 * H + u]; bhn = bh[2 * H + u];
            }
        }
        sb[l][0][ul] = br; sb[l][1][ul] = bz; sb[l][2][ul] = bxn; sb[l][3][ul] = bhn;
    }
    __syncthreads();

    unsigned* mycnt = cnt + bg * 32;   // 128B-strided counters

    auto put_hg = [&](const f32x4& a0, const f32x4& a1) {
        float* d = hg[nt * 2 + part];
        int ul = lane & 15, mrow = (lane >> 4) * 4;
        #pragma unroll
        for (int r = 0; r < 4; r++) {
            d[(mrow + r) * 17 + ul]      = a0[r];
            d[(16 + mrow + r) * 17 + ul] = a1[r];
        }
    };

    for (int s = 0; s < T_STEPS + 2; ++s) {
        const bool hasL0 = (s < T_STEPS);
        const bool hasL1 = (s >= 1 && s <= T_STEPS);
        const bool hasL2 = (s >= 2);

        // ---- stage SA <- ysA[s-1] (cached; fresh lines each step)
        if (s <= T_STEPS) {
            s16x8 preA[6];
            int tprev = s - 1;
            #pragma unroll
            for (int i = 0; i < 6; i++) {
                int c = tid + i * 384;
                s16x8 v = z8;
                if (c < 2048 && tprev >= 0) {
                    int r = c >> 6, cc = c & 63;
                    v = *(const s16x8*)&ysA[((size_t)tprev * BATCH + b0 + r) * HP + cc * 8];
                }
                preA[i] = v;
            }
            #pragma unroll
            for (int i = 0; i < 6; i++) {
                int c = tid + i * 384;
                if (c < 2048) {
                    int r = c >> 6, cc = c & 63;
                    *(s16x8*)&sh[r * 520 + cc * 8] = preA[i];
                }
            }
        }
        __syncthreads();                                   // (a) SA ready

        // ---- layer 0 MFMA: t = s, h from SA (k split across parts)
        if (hasL0) {
            f32x4 a0 = {0.f,0.f,0.f,0.f}, a1 = {0.f,0.f,0.f,0.f};
            #pragma unroll
            for (int i = 0; i < 8; i++) {
                int kk = part * 8 + i;
                s16x8 x0 = *(const s16x8*)&sh[arow * 520 + kk * 32 + acol];
                s16x8 x1 = *(const s16x8*)&sh[(16 + arow) * 520 + kk * 32 + acol];
                a0 = __builtin_amdgcn_mfma_f32_16x16x32_bf16(x0, w0f[i], a0, 0, 0, 0);
                a1 = __builtin_amdgcn_mfma_f32_16x16x32_bf16(x1, w0f[i], a1, 0, 0, 0);
            }
            put_hg(a0, a1);
        }
        // ---- prefetch SC <- ysA[s-3] (BYPASS: lines were re-written by l2)
        s16x8 preC[6];
        {
            int tprev = s - 3;
            #pragma unroll
            for (int i = 0; i < 6; i++) {
                int c = tid + i * 384;
                s16x8 v = z8;
                if (hasL2 && c < 2048 && tprev >= 0) {
                    int r = c >> 6, cc = c & 63;
                    const ull* p = (const ull*)&ysA[((size_t)tprev * BATCH + b0 + r) * HP + cc * 8];
                    union { ull q[2]; s16x8 v; } uu;
                    uu.q[0] = __hip_atomic_load(p,     __ATOMIC_RELAXED, __HIP_MEMORY_SCOPE_AGENT);
                    uu.q[1] = __hip_atomic_load(p + 1, __ATOMIC_RELAXED, __HIP_MEMORY_SCOPE_AGENT);
                    v = uu.v;
                }
                preC[i] = v;
            }
        }
        __syncthreads();                                   // (b) hg0 ready

        // ---- layer 0 gate: out -> ysA[s] (sc1)
        if (hasL0) {
            short* dst = ysA + (size_t)s * BATCH * HP;
            for (int idx = tid; idx < 256; idx += 384) {
                int m = idx >> 3, pr = idx & 7, b = b0 + m;
                unsigned pk = 0;
                #pragma unroll
                for (int e = 0; e < 2; e++) {
                    int ul = pr * 2 + e, u = j * 16 + ul, mo = m * 17 + ul;
                    float hv = 0.f;
                    if (u < H) {
                        float hr = hg[0][mo] + hg[1][mo];
                        float hz = hg[2][mo] + hg[3][mo];
                        float hn = hg[4][mo] + hg[5][mo];
                        float r = sigm(sg0[m * 48 + ul] + hr);
                        float z = sigm(sg0[m * 48 + 16 + ul] + hz);
                        float n = tanh_fast(sg0[m * 48 + 32 + ul] + r * (hn + sb[0][3][ul]));
                        float hold = bf2f(sh[m * 520 + u]);
                        hv = (1.f - z) * n + z * hold;
                    }
                    pk |= ((unsigned)(unsigned short)f2bf(hv)) << (16 * e);
                }
                __hip_atomic_store((unsigned*)&dst[(size_t)b * HP + j * 16 + pr * 2], pk,
                                   __ATOMIC_RELAXED, __HIP_MEMORY_SCOPE_AGENT);
            }
        }
        __syncthreads();                                   // (c) gate0 done with hg/sh

        // ---- layer 1 MFMA: t = s-1; x from SA(LDS), h direct cached ysB[s-2]
        if (hasL1) {
            f32x4 a0 = {0.f,0.f,0.f,0.f}, a1 = {0.f,0.f,0.f,0.f};
            if (part == 0) {
                #pragma unroll
                for (int kk = 0; kk < 16; kk++) {
                    s16x8 x0 = *(const s16x8*)&sh[arow * 520 + kk * 32 + acol];
                    s16x8 x1 = *(const s16x8*)&sh[(16 + arow) * 520 + kk * 32 + acol];
                    a0 = __builtin_amdgcn_mfma_f32_16x16x32_bf16(x0, w1f[kk], a0, 0, 0, 0);
                    a1 = __builtin_amdgcn_mfma_f32_16x16x32_bf16(x1, w1f[kk], a1, 0, 0, 0);
                }
            } else if (s >= 2) {
                const short* hb = ysB + (size_t)(s - 2) * BATCH * HP;
                #pragma unroll
                for (int kk = 0; kk < 16; kk++) {
                    s16x8 h0 = *(const s16x8*)&hb[(size_t)(b0 + arow) * HP + kk * 32 + acol];
                    s16x8 h1 = *(const s16x8*)&hb[(size_t)(b0 + 16 + arow) * HP + kk * 32 + acol];
                    a0 = __builtin_amdgcn_mfma_f32_16x16x32_bf16(h0, w1f[kk], a0, 0, 0, 0);
                    a1 = __builtin_amdgcn_mfma_f32_16x16x32_bf16(h1, w1f[kk], a1, 0, 0, 0);
                }
            }
            put_hg(a0, a1);
        }
        __syncthreads();                                   // (d) hg1 ready, SA dead

        // ---- commit SC into sh (overwrites SA) + layer1 gate -> ysB[s-1]
        if (hasL2) {
            #pragma unroll
            for (int i = 0; i < 6; i++) {
                int c = tid + i * 384;
                if (c < 2048) {
                    int r = c >> 6, cc = c & 63;
                    *(s16x8*)&sh[r * 520 + cc * 8] = preC[i];
                }
            }
        }
        if (hasL1) {
            const short* holdsrc = (s >= 2) ? ysB + (size_t)(s - 2) * BATCH * HP : nullptr;
            short* dst = ysB + (size_t)(s - 1) * BATCH * HP;
            for (int idx = tid; idx < 256; idx += 384) {
                int m = idx >> 3, pr = idx & 7, b = b0 + m;
                unsigned pk = 0;
                #pragma unroll
                for (int e = 0; e < 2; e++) {
                    int ul = pr * 2 + e, u = j * 16 + ul, mo = m * 17 + ul;
                    float hv = 0.f;
                    if (u < H) {
                        float xr = hg[0][mo] + sb[1][0][ul];
                        float hr = hg[1][mo];
                        float xz = hg[2][mo] + sb[1][1][ul];
                        float hz = hg[3][mo];
                        float xn = hg[4][mo] + sb[1][2][ul];
                        float hn = hg[5][mo] + sb[1][3][ul];
                        float r = sigm(xr + hr);
                        float z = sigm(xz + hz);
                        float n = tanh_fast(xn + r * hn);
                        float hold = holdsrc ? bf2f(holdsrc[(size_t)b * HP + u]) : 0.f;
                        hv = (1.f - z) * n + z * hold;
                    }
                    pk |= ((unsigned)(unsigned short)f2bf(hv)) << (16 * e);
                }
                __hip_atomic_store((unsigned*)&dst[(size_t)b * HP + j * 16 + pr * 2], pk,
                                   __ATOMIC_RELAXED, __HIP_MEMORY_SCOPE_AGENT);
            }
        }
        __syncthreads();                                   // (e) SC ready, hg free

        // ---- layer 2 MFMA: t = s-2; x direct cached ysB[s-2] (L2-warm), h from SC(LDS)
        if (hasL2) {
            f32x4 a0 = {0.f,0.f,0.f,0.f}, a1 = {0.f,0.f,0.f,0.f};
            if (part == 0) {
                const short* xb = ysB + (size_t)(s - 2) * BATCH * HP;
                #pragma unroll
                for (int kk = 0; kk < 16; kk++) {
                    s16x8 x0 = *(const s16x8*)&xb[(size_t)(b0 + arow) * HP + kk * 32 + acol];
                    s16x8 x1 = *(const s16x8*)&xb[(size_t)(b0 + 16 + arow) * HP + kk * 32 + acol];
                    a0 = __builtin_amdgcn_mfma_f32_16x16x32_bf16(x0, w2f[kk], a0, 0, 0, 0);
                    a1 = __builtin_amdgcn_mfma_f32_16x16x32_bf16(x1, w2f[kk], a1, 0, 0, 0);
                }
            } else {
                #pragma unroll
                for (int kk = 0; kk < 16; kk++) {
                    s16x8 h0 = *(const s16x8*)&sh[arow * 520 + kk * 32 + acol];
                    s16x8 h1 = *(const s16x8*)&sh[(16 + arow) * 520 + kk * 32 + acol];
                    a0 = __builtin_amdgcn_mfma_f32_16x16x32_bf16(h0, w2f[kk], a0, 0, 0, 0);
                    a1 = __builtin_amdgcn_mfma_f32_16x16x32_bf16(h1, w2f[kk], a1, 0, 0, 0);
                }
            }
            put_hg(a0, a1);
        }
        __syncthreads();                                   // (f) hg2 ready

        // ---- layer 2 gate: out -> ysA[s-2] (sc1; final layer2 output for fc2)
        if (hasL2) {
            short* dst = ysA + (size_t)(s - 2) * BATCH * HP;
            for (int idx = tid; idx < 256; idx += 384) {
                int m = idx >> 3, pr = idx & 7, b = b0 + m;
                unsigned pk = 0;
                #pragma unroll
                for (int e = 0; e < 2; e++) {
                    int ul = pr * 2 + e, u = j * 16 + ul, mo = m * 17 + ul;
                    float hv = 0.f;
                    if (u < H) {
                        float xr = hg[0][mo] + sb[2][0][ul];
                        float hr = hg[1][mo];
                        float xz = hg[2][mo] + sb[2][1][ul];
                        float hz = hg[3][mo];
                        float xn = hg[4][mo] + sb[2][2][ul];
                        float hn = hg[5][mo] + sb[2][3][ul];
                        float r = sigm(xr + hr);
                        float z = sigm(xz + hz);
                        float n = tanh_fast(xn + r * hn);
                        float hold = bf2f(sh[m * 520 + u]);
                        hv = (1.f - z) * n + z * hold;
                    }
                    pk |= ((unsigned)(unsigned short)f2bf(hv)) << (16 * e);
                }
                __hip_atomic_store((unsigned*)&dst[(size_t)b * HP + j * 16 + pr * 2], pk,
                                   __ATOMIC_RELAXED, __HIP_MEMORY_SCOPE_AGENT);
            }
        }
        __syncthreads();                                   // (g) all waves' sc1 stores drained

        // ---- per-bg 32-block barrier: release add + relaxed poll (no invalidate)
        if (tid == 0) {
            __hip_atomic_fetch_add(mycnt, 1u, __ATOMIC_RELEASE, __HIP_MEMORY_SCOPE_AGENT);
            unsigned tgt = 32u * (unsigned)(s + 1);
            while (__hip_atomic_load(mycnt, __ATOMIC_RELAXED, __HIP_MEMORY_SCOPE_AGENT) < tgt) {}
        }
        __syncthreads();                                   // (h)
    }
}

// ---------------------------------------------------------------------------
// fc2 + transpose (reads ysA = layer2 output; fresh kernel => coherent)
// ---------------------------------------------------------------------------
__global__ __launch_bounds__(256, 1)
void k_fc2(const short* __restrict__ ys2, const short* __restrict__ fc2p,
           const float* __restrict__ fc2_b, float* __restrict__ out) {
    int b = blockIdx.x;
    int tid = threadIdx.x, lane = tid & 63, wave = tid >> 6;
    const s16x8 zf = {0, 0, 0, 0, 0, 0, 0, 0};
    for (int ntile = wave; ntile < 18; ntile += 4) {
        int tt = ntile * 16 + (lane & 15);
        s16x8 bf[16];
        for (int kt = 0; kt < 16; kt++) {
            if (tt < T_STEPS)
                bf[kt] = *(const s16x8*)&ys2[((size_t)tt * BATCH + b) * HP + kt * 32 + (lane >> 4) * 8];
            else
                bf[kt] = zf;
        }
        for (int mt = 0; mt < 5; mt++) {
            f32x4 acc = {0.f, 0.f, 0.f, 0.f};
            for (int kt = 0; kt < 16; kt++) {
                s16x8 af = *(const s16x8*)&fc2p[(((size_t)mt * 16 + kt) * 64 + lane) * 8];
                acc = __builtin_amdgcn_mfma_f32_16x16x32_bf16(af, bf[kt], acc, 0, 0, 0);
            }
            int obase = mt * 16 + (lane >> 4) * 4;
            for (int r = 0; r < 4; r++) {
                int o = obase + r;
                if (o < O_OUT && tt < T_STEPS)
                    out[((size_t)b * O_OUT + o) * T_STEPS + tt] = acc[r] + fc2_b[o];
            }
        }
    }
}

// ---------------------------------------------------------------------------
extern "C" void kernel_launch(void* const* d_in, const int* in_sizes, int n_in,
                              void* d_out, int out_size, void* d_ws, size_t ws_size,
                              hipStream_t stream) {
    const float* x     = (const float*)d_in[0];
    const float* fc1_w = (const float*)d_in[1];
    const float* fc1_b = (const float*)d_in[2];
    const float* w_ih0 = (const float*)d_in[3];
    const float* w_hh0 = (const float*)d_in[4];
    const float* b_ih0 = (const float*)d_in[5];
    const float* b_hh0 = (const float*)d_in[6];
    const float* w_ih1 = (const float*)d_in[7];
    const float* w_hh1 = (const float*)d_in[8];
    const float* b_ih1 = (const float*)d_in[9];
    const float* b_hh1 = (const float*)d_in[10];
    const float* w_ih2 = (const float*)d_in[11];
    const float* w_hh2 = (const float*)d_in[12];
    const float* b_ih2 = (const float*)d_in[13];
    const float* b_hh2 = (const float*)d_in[14];
    const float* fc2_w = (const float*)d_in[15];
    const float* fc2_b = (const float*)d_in[16];
    float* out = (float*)d_out;

    char* p = (char*)d_ws;
    auto alloc = [&](size_t bytes) {
        char* r = p; p += (bytes + 255) & ~(size_t)255; return r;
    };
    short* packW0 = (short*)alloc((size_t)32 * 3 * 16 * 64 * 8 * 2);
    short* packW1 = (short*)alloc((size_t)32 * 3 * 32 * 64 * 8 * 2);
    short* packW2 = (short*)alloc((size_t)32 * 3 * 32 * 64 * 8 * 2);
    short* packF  = (short*)alloc((size_t)80 * 64 * 8 * 2);
    float* hin    = (float*)alloc((size_t)BATCH * 64 * 4);
    float* g0     = (float*)alloc((size_t)BATCH * NP * 4);
    unsigned* cnt = (unsigned*)alloc(256 * 4);
    short* ysA    = (short*)alloc((size_t)T_STEPS * BATCH * HP * 2);
    short* ysB    = (short*)alloc((size_t)T_STEPS * BATCH * HP * 2);

    hipMemsetAsync(cnt, 0, 256 * 4, stream);
    k_pack_gru<<<32 * 3 * 16, 64, 0, stream>>>(nullptr, w_hh0, packW0, 16);
    k_pack_gru<<<32 * 3 * 32, 64, 0, stream>>>(w_ih1, w_hh1, packW1, 32);
    k_pack_gru<<<32 * 3 * 32, 64, 0, stream>>>(w_ih2, w_hh2, packW2, 32);
    k_pack_fc2<<<80, 64, 0, stream>>>(fc2_w, packF);
    k_hin<<<BATCH, 64, 0, stream>>>(x, fc1_w, fc1_b, hin);
    k_g0<<<BATCH, 256, 0, stream>>>(hin, w_ih0, b_ih0, g0);

    k_gru_persist<<<256, 384, 0, stream>>>(packW0, packW1, packW2, g0,
                                           b_hh0, b_ih1, b_hh1, b_ih2, b_hh2,
                                           ysA, ysB, cnt);

    k_fc2<<<BATCH, 256, 0, stream>>>(ysA, packF, fc2_b, out);
}

// Round 4
// 3627.888 us; speedup vs baseline: 2.1432x; 1.0020x over previous
//
#include <hip/hip_runtime.h>
#include <hip/hip_bf16.h>
#include <math.h>

#define D_IN 56
#define H    501
#define T_STEPS 277
#define O_OUT 76
#define BATCH 256
#define HP   512    // padded K (hidden) for MFMA
#define NP   1504   // padded 3H

typedef __attribute__((ext_vector_type(8))) short s16x8;
typedef __attribute__((ext_vector_type(4))) float f32x4;
typedef unsigned long long ull;

__device__ __forceinline__ short f2bf(float x) {
    union { float f; unsigned u; } v; v.f = x;
    unsigned r = (v.u + 0x7fffu + ((v.u >> 16) & 1u)) >> 16;
    return (short)r;
}
__device__ __forceinline__ float bf2f(short b) {
    union { unsigned u; float f; } v; v.u = ((unsigned)(unsigned short)b) << 16;
    return v.f;
}
__device__ __forceinline__ float sigm(float x) { return 1.f / (1.f + __expf(-x)); }
__device__ __forceinline__ float tanh_fast(float x) { return 1.f - 2.f / (1.f + __expf(2.f * x)); }

// ---------------------------------------------------------------------------
// Weight packing (unchanged, proven correct)
// ---------------------------------------------------------------------------
__global__ void k_pack_gru(const float* __restrict__ w_ih,
                           const float* __restrict__ w_hh,
                           short* __restrict__ dst, int KT) {
    int tile = blockIdx.x;
    int ktp  = tile % KT;
    int g    = (tile / KT) % 3;
    int j    = tile / (KT * 3);
    int l    = threadIdx.x;
    int u    = j * 16 + (l & 15);
    int row  = g * H + u;
    const float* src; int k0;
    if (KT == 32) {
        if (ktp < 16) { src = w_ih; k0 = ktp * 32; }
        else          { src = w_hh; k0 = (ktp - 16) * 32; }
    } else          { src = w_hh; k0 = ktp * 32; }
    k0 += (l >> 4) * 8;
    short* p = dst + ((size_t)tile * 64 + l) * 8;
    for (int jj = 0; jj < 8; jj++) {
        int k = k0 + jj;
        float v = 0.f;
        if (u < H && k < H) v = src[(size_t)row * H + k];
        p[jj] = f2bf(v);
    }
}

__global__ void k_pack_fc2(const float* __restrict__ w, short* __restrict__ dst) {
    int tile = blockIdx.x;
    int kt = tile % 16, mt = tile / 16;
    int l = threadIdx.x;
    int o = mt * 16 + (l & 15);
    int k0 = kt * 32 + (l >> 4) * 8;
    short* p = dst + ((size_t)tile * 64 + l) * 8;
    for (int jj = 0; jj < 8; jj++) {
        int k = k0 + jj; float v = 0.f;
        if (o < O_OUT && k < H) v = w[(size_t)o * H + k];
        p[jj] = f2bf(v);
    }
}

__global__ void k_hin(const float* __restrict__ x, const float* __restrict__ w,
                      const float* __restrict__ bias, float* __restrict__ hin) {
    int b = blockIdx.x, o = threadIdx.x;
    float acc = 0.f;
    if (o < D_IN) {
        acc = bias[o];
        for (int k = 0; k < D_IN; k++) acc += x[b * D_IN + k] * w[o * D_IN + k];
        acc = fmaxf(acc, 0.f);
    }
    hin[b * 64 + o] = (o < D_IN) ? acc : 0.f;
}

__global__ void k_g0(const float* __restrict__ hin, const float* __restrict__ w_ih0,
                     const float* __restrict__ b_ih0, float* __restrict__ g0) {
    int b = blockIdx.x, tid = threadIdx.x;
    __shared__ float shx[D_IN];
    if (tid < D_IN) shx[tid] = hin[b * 64 + tid];
    __syncthreads();
    for (int o = tid; o < NP; o += 256) {
        float acc = 0.f;
        if (o < 3 * H) {
            acc = b_ih0[o];
            for (int k = 0; k < D_IN; k++) acc += shx[k] * w_ih0[(size_t)o * D_IN + k];
        }
        g0[(size_t)b * NP + o] = acc;
    }
}

// ---------------------------------------------------------------------------
// Persistent pipelined GRU with epoch-addressed fence-free exchange.
// R4 change: weight fragments re-pinned via asm "+v" EVERY iteration so the
// compiler cannot sink the 40 fragment loads (240 KB/block, L3-latency
// chains) back into the K-loops. 160 VGPRs stay live for the whole t-loop.
// ---------------------------------------------------------------------------
__global__ __launch_bounds__(384, 1)
void k_gru_persist(const short* __restrict__ packW0,
                   const short* __restrict__ packW1,
                   const short* __restrict__ packW2,
                   const float* __restrict__ g0,
                   const float* __restrict__ b_hh0,
                   const float* __restrict__ b_ih1, const float* __restrict__ b_hh1,
                   const float* __restrict__ b_ih2, const float* __restrict__ b_hh2,
                   short* __restrict__ ysA,    // layer0 out at t, overwritten by layer2 at t (step t+2)
                   short* __restrict__ ysB,    // layer1 out
                   unsigned* __restrict__ cnt) {
    const int bg   = blockIdx.x & 7;
    const int j    = blockIdx.x >> 3;
    const int b0   = bg * 32;
    const int tid  = threadIdx.x;
    const int lane = tid & 63;
    const int wave = tid >> 6;
    const int nt   = wave >> 1;        // gate 0..2
    const int part = wave & 1;
    const int arow = lane & 15;
    const int acol = (lane >> 4) * 8;
    const s16x8 z8 = {0, 0, 0, 0, 0, 0, 0, 0};

    __shared__ __align__(16) short sh[32 * 520];   // one staging buffer (33,280 B)
    __shared__ float hg[6][544];                   // MFMA results (13,056 B)
    __shared__ float sg0[32 * 48];                 // layer0 x-gates (6,144 B)
    __shared__ float sb[3][4][16];                 // folded biases

    // ---- weight fragments -> VGPRs, pinned for the whole kernel
    s16x8 w0f[8], w1f[16], w2f[16];
    {
        const short* p0 = packW0 + ((size_t)((j * 3 + nt) * 16 + part * 8) * 64) * 8;
        #pragma unroll
        for (int i = 0; i < 8; i++)  w0f[i] = *(const s16x8*)&p0[((size_t)i * 64 + lane) * 8];
        const short* p1 = packW1 + ((size_t)((j * 3 + nt) * 32 + part * 16) * 64) * 8;
        #pragma unroll
        for (int i = 0; i < 16; i++) w1f[i] = *(const s16x8*)&p1[((size_t)i * 64 + lane) * 8];
        const short* p2 = packW2 + ((size_t)((j * 3 + nt) * 32 + part * 16) * 64) * 8;
        #pragma unroll
        for (int i = 0; i < 16; i++) w2f[i] = *(const s16x8*)&p2[((size_t)i * 64 + lane) * 8];
    }
    // ---- layer0 x-gate constants (g0 + b_hh0 folded for r,z)
    for (int c = tid; c < 32 * 48; c += 384) {
        int m = c / 48, col = c % 48;
        int g = col >> 4, ul = col & 15;
        int u = j * 16 + ul;
        float v = 0.f;
        if (u < H) {
            v = g0[(size_t)(b0 + m) * NP + g * H + u];
            if (g == 0) v += b_hh0[u];
            else if (g == 1) v += b_hh0[H + u];
        }
        sg0[m * 48 + col] = v;
    }
    if (tid < 48) {
        int l = tid >> 4, ul = tid & 15, u = j * 16 + ul;
        float br = 0.f, bz = 0.f, bxn = 0.f, bhn = 0.f;
        if (u < H) {
            if (l == 0) bhn = b_hh0[2 * H + u];
            else {
                const float* bi = (l == 1) ? b_ih1 : b_ih2;
                const float* bh = (l == 1) ? b_hh1 : b_hh2;
                br = bi[u] + bh[u]; bz = bi[H + u] + bh[H + u];
                bxn = bi[2 * H + u]; bhn = bh[2 * H + u];
            }
        }
        sb[l][0][ul] = br; sb[l][1][ul] = bz; sb[l][2][ul] = bxn; sb[l][3][ul] = bhn;
    }
    __syncthreads();

    unsigned* mycnt = cnt + bg * 32;   // 128B-strided counters

    auto put_hg = [&](const f32x4& a0, const f32x4& a1) {
        float* d = hg[nt * 2 + part];
        int ul = lane & 15, mrow = (lane >> 4) * 4;
        #pragma unroll
        for (int r = 0; r < 4; r++) {
            d[(mrow + r) * 17 + ul]      = a0[r];
            d[(16 + mrow + r) * 17 + ul] = a1[r];
        }
    };

    for (int s = 0; s < T_STEPS + 2; ++s) {
        // ---- re-pin weight fragments: asm nominally rewrites them, so the
        // compiler must keep them in VGPRs across iterations (cannot reload).
        #pragma unroll
        for (int i = 0; i < 8; i++)  asm volatile("" : "+v"(w0f[i]));
        #pragma unroll
        for (int i = 0; i < 16; i++) asm volatile("" : "+v"(w1f[i]));
        #pragma unroll
        for (int i = 0; i < 16; i++) asm volatile("" : "+v"(w2f[i]));

        const bool hasL0 = (s < T_STEPS);
        const bool hasL1 = (s >= 1 && s <= T_STEPS);
        const bool hasL2 = (s >= 2);

        // ---- stage SA <- ysA[s-1] (cached; fresh lines each step)
        if (s <= T_STEPS) {
            s16x8 preA[6];
            int tprev = s - 1;
            #pragma unroll
            for (int i = 0; i < 6; i++) {
                int c = tid + i * 384;
                s16x8 v = z8;
                if (c < 2048 && tprev >= 0) {
                    int r = c >> 6, cc = c & 63;
                    v = *(const s16x8*)&ysA[((size_t)tprev * BATCH + b0 + r) * HP + cc * 8];
                }
                preA[i] = v;
            }
            #pragma unroll
            for (int i = 0; i < 6; i++) {
                int c = tid + i * 384;
                if (c < 2048) {
                    int r = c >> 6, cc = c & 63;
                    *(s16x8*)&sh[r * 520 + cc * 8] = preA[i];
                }
            }
        }
        __syncthreads();                                   // (a) SA ready

        // ---- layer 0 MFMA: t = s, h from SA (k split across parts)
        if (hasL0) {
            f32x4 a0 = {0.f,0.f,0.f,0.f}, a1 = {0.f,0.f,0.f,0.f};
            #pragma unroll
            for (int i = 0; i < 8; i++) {
                int kk = part * 8 + i;
                s16x8 x0 = *(const s16x8*)&sh[arow * 520 + kk * 32 + acol];
                s16x8 x1 = *(const s16x8*)&sh[(16 + arow) * 520 + kk * 32 + acol];
                a0 = __builtin_amdgcn_mfma_f32_16x16x32_bf16(x0, w0f[i], a0, 0, 0, 0);
                a1 = __builtin_amdgcn_mfma_f32_16x16x32_bf16(x1, w0f[i], a1, 0, 0, 0);
            }
            put_hg(a0, a1);
        }
        // ---- prefetch SC <- ysA[s-3] (BYPASS: lines were re-written by l2)
        s16x8 preC[6];
        {
            int tprev = s - 3;
            #pragma unroll
            for (int i = 0; i < 6; i++) {
                int c = tid + i * 384;
                s16x8 v = z8;
                if (hasL2 && c < 2048 && tprev >= 0) {
                    int r = c >> 6, cc = c & 63;
                    const ull* p = (const ull*)&ysA[((size_t)tprev * BATCH + b0 + r) * HP + cc * 8];
                    union { ull q[2]; s16x8 v; } uu;
                    uu.q[0] = __hip_atomic_load(p,     __ATOMIC_RELAXED, __HIP_MEMORY_SCOPE_AGENT);
                    uu.q[1] = __hip_atomic_load(p + 1, __ATOMIC_RELAXED, __HIP_MEMORY_SCOPE_AGENT);
                    v = uu.v;
                }
                preC[i] = v;
            }
        }
        __syncthreads();                                   // (b) hg0 ready

        // ---- layer 0 gate: out -> ysA[s] (sc1)
        if (hasL0) {
            short* dst = ysA + (size_t)s * BATCH * HP;
            for (int idx = tid; idx < 256; idx += 384) {
                int m = idx >> 3, pr = idx & 7, b = b0 + m;
                unsigned pk = 0;
                #pragma unroll
                for (int e = 0; e < 2; e++) {
                    int ul = pr * 2 + e, u = j * 16 + ul, mo = m * 17 + ul;
                    float hv = 0.f;
                    if (u < H) {
                        float hr = hg[0][mo] + hg[1][mo];
                        float hz = hg[2][mo] + hg[3][mo];
                        float hn = hg[4][mo] + hg[5][mo];
                        float r = sigm(sg0[m * 48 + ul] + hr);
                        float z = sigm(sg0[m * 48 + 16 + ul] + hz);
                        float n = tanh_fast(sg0[m * 48 + 32 + ul] + r * (hn + sb[0][3][ul]));
                        float hold = bf2f(sh[m * 520 + u]);
                        hv = (1.f - z) * n + z * hold;
                    }
                    pk |= ((unsigned)(unsigned short)f2bf(hv)) << (16 * e);
                }
                __hip_atomic_store((unsigned*)&dst[(size_t)b * HP + j * 16 + pr * 2], pk,
                                   __ATOMIC_RELAXED, __HIP_MEMORY_SCOPE_AGENT);
            }
        }
        __syncthreads();                                   // (c) gate0 done with hg/sh

        // ---- layer 1 MFMA: t = s-1; x from SA(LDS), h direct cached ysB[s-2]
        if (hasL1) {
            f32x4 a0 = {0.f,0.f,0.f,0.f}, a1 = {0.f,0.f,0.f,0.f};
            if (part == 0) {
                #pragma unroll
                for (int kk = 0; kk < 16; kk++) {
                    s16x8 x0 = *(const s16x8*)&sh[arow * 520 + kk * 32 + acol];
                    s16x8 x1 = *(const s16x8*)&sh[(16 + arow) * 520 + kk * 32 + acol];
                    a0 = __builtin_amdgcn_mfma_f32_16x16x32_bf16(x0, w1f[kk], a0, 0, 0, 0);
                    a1 = __builtin_amdgcn_mfma_f32_16x16x32_bf16(x1, w1f[kk], a1, 0, 0, 0);
                }
            } else if (s >= 2) {
                const short* hb = ysB + (size_t)(s - 2) * BATCH * HP;
                #pragma unroll
                for (int kk = 0; kk < 16; kk++) {
                    s16x8 h0 = *(const s16x8*)&hb[(size_t)(b0 + arow) * HP + kk * 32 + acol];
                    s16x8 h1 = *(const s16x8*)&hb[(size_t)(b0 + 16 + arow) * HP + kk * 32 + acol];
                    a0 = __builtin_amdgcn_mfma_f32_16x16x32_bf16(h0, w1f[kk], a0, 0, 0, 0);
                    a1 = __builtin_amdgcn_mfma_f32_16x16x32_bf16(h1, w1f[kk], a1, 0, 0, 0);
                }
            }
            put_hg(a0, a1);
        }
        __syncthreads();                                   // (d) hg1 ready, SA dead

        // ---- commit SC into sh (overwrites SA) + layer1 gate -> ysB[s-1]
        if (hasL2) {
            #pragma unroll
            for (int i = 0; i < 6; i++) {
                int c = tid + i * 384;
                if (c < 2048) {
                    int r = c >> 6, cc = c & 63;
                    *(s16x8*)&sh[r * 520 + cc * 8] = preC[i];
                }
            }
        }
        if (hasL1) {
            const short* holdsrc = (s >= 2) ? ysB + (size_t)(s - 2) * BATCH * HP : nullptr;
            short* dst = ysB + (size_t)(s - 1) * BATCH * HP;
            for (int idx = tid; idx < 256; idx += 384) {
                int m = idx >> 3, pr = idx & 7, b = b0 + m;
                unsigned pk = 0;
                #pragma unroll
                for (int e = 0; e < 2; e++) {
                    int ul = pr * 2 + e, u = j * 16 + ul, mo = m * 17 + ul;
                    float hv = 0.f;
                    if (u < H) {
                        float xr = hg[0][mo] + sb[1][0][ul];
                        float hr = hg[1][mo];
                        float xz = hg[2][mo] + sb[1][1][ul];
                        float hz = hg[3][mo];
                        float xn = hg[4][mo] + sb[1][2][ul];
                        float hn = hg[5][mo] + sb[1][3][ul];
                        float r = sigm(xr + hr);
                        float z = sigm(xz + hz);
                        float n = tanh_fast(xn + r * hn);
                        float hold = holdsrc ? bf2f(holdsrc[(size_t)b * HP + u]) : 0.f;
                        hv = (1.f - z) * n + z * hold;
                    }
                    pk |= ((unsigned)(unsigned short)f2bf(hv)) << (16 * e);
                }
                __hip_atomic_store((unsigned*)&dst[(size_t)b * HP + j * 16 + pr * 2], pk,
                                   __ATOMIC_RELAXED, __HIP_MEMORY_SCOPE_AGENT);
            }
        }
        __syncthreads();                                   // (e) SC ready, hg free

        // ---- layer 2 MFMA: t = s-2; x direct cached ysB[s-2] (L2-warm), h from SC(LDS)
        if (hasL2) {
            f32x4 a0 = {0.f,0.f,0.f,0.f}, a1 = {0.f,0.f,0.f,0.f};
            if (part == 0) {
                const short* xb = ysB + (size_t)(s - 2) * BATCH * HP;
                #pragma unroll
                for (int kk = 0; kk < 16; kk++) {
                    s16x8 x0 = *(const s16x8*)&xb[(size_t)(b0 + arow) * HP + kk * 32 + acol];
                    s16x8 x1 = *(const s16x8*)&xb[(size_t)(b0 + 16 + arow) * HP + kk * 32 + acol];
                    a0 = __builtin_amdgcn_mfma_f32_16x16x32_bf16(x0, w2f[kk], a0, 0, 0, 0);
                    a1 = __builtin_amdgcn_mfma_f32_16x16x32_bf16(x1, w2f[kk], a1, 0, 0, 0);
                }
            } else {
                #pragma unroll
                for (int kk = 0; kk < 16; kk++) {
                    s16x8 h0 = *(const s16x8*)&sh[arow * 520 + kk * 32 + acol];
                    s16x8 h1 = *(const s16x8*)&sh[(16 + arow) * 520 + kk * 32 + acol];
                    a0 = __builtin_amdgcn_mfma_f32_16x16x32_bf16(h0, w2f[kk], a0, 0, 0, 0);
                    a1 = __builtin_amdgcn_mfma_f32_16x16x32_bf16(h1, w2f[kk], a1, 0, 0, 0);
                }
            }
            put_hg(a0, a1);
        }
        __syncthreads();                                   // (f) hg2 ready

        // ---- layer 2 gate: out -> ysA[s-2] (sc1; final layer2 output for fc2)
        if (hasL2) {
            short* dst = ysA + (size_t)(s - 2) * BATCH * HP;
            for (int idx = tid; idx < 256; idx += 384) {
                int m = idx >> 3, pr = idx & 7, b = b0 + m;
                unsigned pk = 0;
                #pragma unroll
                for (int e = 0; e < 2; e++) {
                    int ul = pr * 2 + e, u = j * 16 + ul, mo = m * 17 + ul;
                    float hv = 0.f;
                    if (u < H) {
                        float xr = hg[0][mo] + sb[2][0][ul];
                        float hr = hg[1][mo];
                        float xz = hg[2][mo] + sb[2][1][ul];
                        float hz = hg[3][mo];
                        float xn = hg[4][mo] + sb[2][2][ul];
                        float hn = hg[5][mo] + sb[2][3][ul];
                        float r = sigm(xr + hr);
                        float z = sigm(xz + hz);
                        float n = tanh_fast(xn + r * hn);
                        float hold = bf2f(sh[m * 520 + u]);
                        hv = (1.f - z) * n + z * hold;
                    }
                    pk |= ((unsigned)(unsigned short)f2bf(hv)) << (16 * e);
                }
                __hip_atomic_store((unsigned*)&dst[(size_t)b * HP + j * 16 + pr * 2], pk,
                                   __ATOMIC_RELAXED, __HIP_MEMORY_SCOPE_AGENT);
            }
        }
        __syncthreads();                                   // (g) all waves' sc1 stores drained

        // ---- per-bg 32-block barrier: release add + relaxed poll (no invalidate)
        if (tid == 0) {
            __hip_atomic_fetch_add(mycnt, 1u, __ATOMIC_RELEASE, __HIP_MEMORY_SCOPE_AGENT);
            unsigned tgt = 32u * (unsigned)(s + 1);
            while (__hip_atomic_load(mycnt, __ATOMIC_RELAXED, __HIP_MEMORY_SCOPE_AGENT) < tgt) {}
        }
        __syncthreads();                                   // (h)
    }
}

// ---------------------------------------------------------------------------
// fc2 + transpose (reads ysA = layer2 output; fresh kernel => coherent)
// ---------------------------------------------------------------------------
__global__ __launch_bounds__(256, 1)
void k_fc2(const short* __restrict__ ys2, const short* __restrict__ fc2p,
           const float* __restrict__ fc2_b, float* __restrict__ out) {
    int b = blockIdx.x;
    int tid = threadIdx.x, lane = tid & 63, wave = tid >> 6;
    const s16x8 zf = {0, 0, 0, 0, 0, 0, 0, 0};
    for (int ntile = wave; ntile < 18; ntile += 4) {
        int tt = ntile * 16 + (lane & 15);
        s16x8 bf[16];
        for (int kt = 0; kt < 16; kt++) {
            if (tt < T_STEPS)
                bf[kt] = *(const s16x8*)&ys2[((size_t)tt * BATCH + b) * HP + kt * 32 + (lane >> 4) * 8];
            else
                bf[kt] = zf;
        }
        for (int mt = 0; mt < 5; mt++) {
            f32x4 acc = {0.f, 0.f, 0.f, 0.f};
            for (int kt = 0; kt < 16; kt++) {
                s16x8 af = *(const s16x8*)&fc2p[(((size_t)mt * 16 + kt) * 64 + lane) * 8];
                acc = __builtin_amdgcn_mfma_f32_16x16x32_bf16(af, bf[kt], acc, 0, 0, 0);
            }
            int obase = mt * 16 + (lane >> 4) * 4;
            for (int r = 0; r < 4; r++) {
                int o = obase + r;
                if (o < O_OUT && tt < T_STEPS)
                    out[((size_t)b * O_OUT + o) * T_STEPS + tt] = acc[r] + fc2_b[o];
            }
        }
    }
}

// ---------------------------------------------------------------------------
extern "C" void kernel_launch(void* const* d_in, const int* in_sizes, int n_in,
                              void* d_out, int out_size, void* d_ws, size_t ws_size,
                              hipStream_t stream) {
    const float* x     = (const float*)d_in[0];
    const float* fc1_w = (const float*)d_in[1];
    const float* fc1_b = (const float*)d_in[2];
    const float* w_ih0 = (const float*)d_in[3];
    const float* w_hh0 = (const float*)d_in[4];
    const float* b_ih0 = (const float*)d_in[5];
    const float* b_hh0 = (const float*)d_in[6];
    const float* w_ih1 = (const float*)d_in[7];
    const float* w_hh1 = (const float*)d_in[8];
    const float* b_ih1 = (const float*)d_in[9];
    const float* b_hh1 = (const float*)d_in[10];
    const float* w_ih2 = (const float*)d_in[11];
    const float* w_hh2 = (const float*)d_in[12];
    const float* b_ih2 = (const float*)d_in[13];
    const float* b_hh2 = (const float*)d_in[14];
    const float* fc2_w = (const float*)d_in[15];
    const float* fc2_b = (const float*)d_in[16];
    float* out = (float*)d_out;

    char* p = (char*)d_ws;
    auto alloc = [&](size_t bytes) {
        char* r = p; p += (bytes + 255) & ~(size_t)255; return r;
    };
    short* packW0 = (short*)alloc((size_t)32 * 3 * 16 * 64 * 8 * 2);
    short* packW1 = (short*)alloc((size_t)32 * 3 * 32 * 64 * 8 * 2);
    short* packW2 = (short*)alloc((size_t)32 * 3 * 32 * 64 * 8 * 2);
    short* packF  = (short*)alloc((size_t)80 * 64 * 8 * 2);
    float* hin    = (float*)alloc((size_t)BATCH * 64 * 4);
    float* g0     = (float*)alloc((size_t)BATCH * NP * 4);
    unsigned* cnt = (unsigned*)alloc(256 * 4);
    short* ysA    = (short*)alloc((size_t)T_STEPS * BATCH * HP * 2);
    short* ysB    = (short*)alloc((size_t)T_STEPS * BATCH * HP * 2);

    hipMemsetAsync(cnt, 0, 256 * 4, stream);
    k_pack_gru<<<32 * 3 * 16, 64, 0, stream>>>(nullptr, w_hh0, packW0, 16);
    k_pack_gru<<<32 * 3 * 32, 64, 0, stream>>>(w_ih1, w_hh1, packW1, 32);
    k_pack_gru<<<32 * 3 * 32, 64, 0, stream>>>(w_ih2, w_hh2, packW2, 32);
    k_pack_fc2<<<80, 64, 0, stream>>>(fc2_w, packF);
    k_hin<<<BATCH, 64, 0, stream>>>(x, fc1_w, fc1_b, hin);
    k_g0<<<BATCH, 256, 0, stream>>>(hin, w_ih0, b_ih0, g0);

    k_gru_persist<<<256, 384, 0, stream>>>(packW0, packW1, packW2, g0,
                                           b_hh0, b_ih1, b_hh1, b_ih2, b_hh2,
                                           ysA, ysB, cnt);

    k_fc2<<<BATCH, 256, 0, stream>>>(ysA, packF, fc2_b, out);
}

// Round 5
// 3398.992 us; speedup vs baseline: 2.2876x; 1.0673x over previous
//
#include <hip/hip_runtime.h>
#include <hip/hip_bf16.h>
#include <math.h>

#define D_IN 56
#define H    501
#define T_STEPS 277
#define O_OUT 76
#define BATCH 256
#define HP   512    // padded K (hidden) for MFMA
#define NP   1504   // padded 3H

typedef __attribute__((ext_vector_type(8))) short s16x8;
typedef __attribute__((ext_vector_type(4))) float f32x4;
typedef unsigned long long ull;

__device__ __forceinline__ short f2bf(float x) {
    union { float f; unsigned u; } v; v.f = x;
    unsigned r = (v.u + 0x7fffu + ((v.u >> 16) & 1u)) >> 16;
    return (short)r;
}
__device__ __forceinline__ float bf2f(short b) {
    union { unsigned u; float f; } v; v.u = ((unsigned)(unsigned short)b) << 16;
    return v.f;
}
__device__ __forceinline__ float sigm(float x) { return 1.f / (1.f + __expf(-x)); }
__device__ __forceinline__ float tanh_fast(float x) { return 1.f - 2.f / (1.f + __expf(2.f * x)); }

// ---------------------------------------------------------------------------
// Weight packing (unchanged, proven correct)
// ---------------------------------------------------------------------------
__global__ void k_pack_gru(const float* __restrict__ w_ih,
                           const float* __restrict__ w_hh,
                           short* __restrict__ dst, int KT) {
    int tile = blockIdx.x;
    int ktp  = tile % KT;
    int g    = (tile / KT) % 3;
    int j    = tile / (KT * 3);
    int l    = threadIdx.x;
    int u    = j * 16 + (l & 15);
    int row  = g * H + u;
    const float* src; int k0;
    if (KT == 32) {
        if (ktp < 16) { src = w_ih; k0 = ktp * 32; }
        else          { src = w_hh; k0 = (ktp - 16) * 32; }
    } else          { src = w_hh; k0 = ktp * 32; }
    k0 += (l >> 4) * 8;
    short* p = dst + ((size_t)tile * 64 + l) * 8;
    for (int jj = 0; jj < 8; jj++) {
        int k = k0 + jj;
        float v = 0.f;
        if (u < H && k < H) v = src[(size_t)row * H + k];
        p[jj] = f2bf(v);
    }
}

__global__ void k_pack_fc2(const float* __restrict__ w, short* __restrict__ dst) {
    int tile = blockIdx.x;
    int kt = tile % 16, mt = tile / 16;
    int l = threadIdx.x;
    int o = mt * 16 + (l & 15);
    int k0 = kt * 32 + (l >> 4) * 8;
    short* p = dst + ((size_t)tile * 64 + l) * 8;
    for (int jj = 0; jj < 8; jj++) {
        int k = k0 + jj; float v = 0.f;
        if (o < O_OUT && k < H) v = w[(size_t)o * H + k];
        p[jj] = f2bf(v);
    }
}

__global__ void k_hin(const float* __restrict__ x, const float* __restrict__ w,
                      const float* __restrict__ bias, float* __restrict__ hin) {
    int b = blockIdx.x, o = threadIdx.x;
    float acc = 0.f;
    if (o < D_IN) {
        acc = bias[o];
        for (int k = 0; k < D_IN; k++) acc += x[b * D_IN + k] * w[o * D_IN + k];
        acc = fmaxf(acc, 0.f);
    }
    hin[b * 64 + o] = (o < D_IN) ? acc : 0.f;
}

__global__ void k_g0(const float* __restrict__ hin, const float* __restrict__ w_ih0,
                     const float* __restrict__ b_ih0, float* __restrict__ g0) {
    int b = blockIdx.x, tid = threadIdx.x;
    __shared__ float shx[D_IN];
    if (tid < D_IN) shx[tid] = hin[b * 64 + tid];
    __syncthreads();
    for (int o = tid; o < NP; o += 256) {
        float acc = 0.f;
        if (o < 3 * H) {
            acc = b_ih0[o];
            for (int k = 0; k < D_IN; k++) acc += shx[k] * w_ih0[(size_t)o * D_IN + k];
        }
        g0[(size_t)b * NP + o] = acc;
    }
}

// ---------------------------------------------------------------------------
// Persistent pipelined GRU, epoch-addressed fence-free exchange.
// R5 changes:
//  (1) weight fragments pinned in AGPRs ("+a" asm, re-asserted per iter) —
//      gfx950 MFMA reads B directly from AGPRs; kills 240KB/block/step of
//      weight re-streaming from L2/L3.
//  (2) XCD-local weight mapping: j = (blk&7)*4 + ((blk>>3)&3), bg = blk>>5
//      => per-XCD weight working set 960KB (L2-resident) if (1) fails.
//  (3) barrier: RELEASE fetch_add (implied L2 writeback) replaced by
//      explicit s_waitcnt vmcnt(0) + RELAXED fetch_add; __syncthreads
//      already drains other waves' stores (all exchange stores are sc1).
// ---------------------------------------------------------------------------
__global__ __launch_bounds__(384, 1)
void k_gru_persist(const short* __restrict__ packW0,
                   const short* __restrict__ packW1,
                   const short* __restrict__ packW2,
                   const float* __restrict__ g0,
                   const float* __restrict__ b_hh0,
                   const float* __restrict__ b_ih1, const float* __restrict__ b_hh1,
                   const float* __restrict__ b_ih2, const float* __restrict__ b_hh2,
                   short* __restrict__ ysA,    // layer0 out at t, overwritten by layer2 at t (step t+2)
                   short* __restrict__ ysB,    // layer1 out
                   unsigned* __restrict__ cnt) {
    const int bg   = blockIdx.x >> 5;                          // batch group 0..7
    const int j    = ((blockIdx.x & 7) << 2) | ((blockIdx.x >> 3) & 3); // unit slice, XCD-local
    const int b0   = bg * 32;
    const int tid  = threadIdx.x;
    const int lane = tid & 63;
    const int wave = tid >> 6;
    const int nt   = wave >> 1;        // gate 0..2
    const int part = wave & 1;
    const int arow = lane & 15;
    const int acol = (lane >> 4) * 8;
    const s16x8 z8 = {0, 0, 0, 0, 0, 0, 0, 0};

    __shared__ __align__(16) short sh[32 * 520];   // one staging buffer (33,280 B)
    __shared__ float hg[6][544];                   // MFMA results (13,056 B)
    __shared__ float sg0[32 * 48];                 // layer0 x-gates (6,144 B)
    __shared__ float sb[3][4][16];                 // folded biases

    // ---- weight fragments -> AGPRs, pinned for the whole kernel
    s16x8 w0f[8], w1f[16], w2f[16];
    {
        const short* p0 = packW0 + ((size_t)((j * 3 + nt) * 16 + part * 8) * 64) * 8;
        #pragma unroll
        for (int i = 0; i < 8; i++)  w0f[i] = *(const s16x8*)&p0[((size_t)i * 64 + lane) * 8];
        const short* p1 = packW1 + ((size_t)((j * 3 + nt) * 32 + part * 16) * 64) * 8;
        #pragma unroll
        for (int i = 0; i < 16; i++) w1f[i] = *(const s16x8*)&p1[((size_t)i * 64 + lane) * 8];
        const short* p2 = packW2 + ((size_t)((j * 3 + nt) * 32 + part * 16) * 64) * 8;
        #pragma unroll
        for (int i = 0; i < 16; i++) w2f[i] = *(const s16x8*)&p2[((size_t)i * 64 + lane) * 8];
    }
    // ---- layer0 x-gate constants (g0 + b_hh0 folded for r,z)
    for (int c = tid; c < 32 * 48; c += 384) {
        int m = c / 48, col = c % 48;
        int g = col >> 4, ul = col & 15;
        int u = j * 16 + ul;
        float v = 0.f;
        if (u < H) {
            v = g0[(size_t)(b0 + m) * NP + g * H + u];
            if (g == 0) v += b_hh0[u];
            else if (g == 1) v += b_hh0[H + u];
        }
        sg0[m * 48 + col] = v;
    }
    if (tid < 48) {
        int l = tid >> 4, ul = tid & 15, u = j * 16 + ul;
        float br = 0.f, bz = 0.f, bxn = 0.f, bhn = 0.f;
        if (u < H) {
            if (l == 0) bhn = b_hh0[2 * H + u];
            else {
                const float* bi = (l == 1) ? b_ih1 : b_ih2;
                const float* bh = (l == 1) ? b_hh1 : b_hh2;
                br = bi[u] + bh[u]; bz = bi[H + u] + bh[H + u];
                bxn = bi[2 * H + u]; bhn = bh[2 * H + u];
            }
        }
        sb[l][0][ul] = br; sb[l][1][ul] = bz; sb[l][2][ul] = bxn; sb[l][3][ul] = bhn;
    }
    __syncthreads();

    unsigned* mycnt = cnt + bg * 32;   // 128B-strided counters

    auto put_hg = [&](const f32x4& a0, const f32x4& a1) {
        float* d = hg[nt * 2 + part];
        int ul = lane & 15, mrow = (lane >> 4) * 4;
        #pragma unroll
        for (int r = 0; r < 4; r++) {
            d[(mrow + r) * 17 + ul]      = a0[r];
            d[(16 + mrow + r) * 17 + ul] = a1[r];
        }
    };

    for (int s = 0; s < T_STEPS + 2; ++s) {
        // ---- re-pin weight fragments in AGPRs: the asm nominally rewrites
        // them each iteration, so they must stay register-resident (AGPR
        // class; RA avoids AGPR->memory spills, and gfx950 MFMA reads B
        // directly from AGPRs).
        #pragma unroll
        for (int i = 0; i < 8; i++)  asm volatile("" : "+a"(w0f[i]));
        #pragma unroll
        for (int i = 0; i < 16; i++) asm volatile("" : "+a"(w1f[i]));
        #pragma unroll
        for (int i = 0; i < 16; i++) asm volatile("" : "+a"(w2f[i]));

        const bool hasL0 = (s < T_STEPS);
        const bool hasL1 = (s >= 1 && s <= T_STEPS);
        const bool hasL2 = (s >= 2);

        // ---- stage SA <- ysA[s-1] (cached; fresh lines each step)
        if (s <= T_STEPS) {
            s16x8 preA[6];
            int tprev = s - 1;
            #pragma unroll
            for (int i = 0; i < 6; i++) {
                int c = tid + i * 384;
                s16x8 v = z8;
                if (c < 2048 && tprev >= 0) {
                    int r = c >> 6, cc = c & 63;
                    v = *(const s16x8*)&ysA[((size_t)tprev * BATCH + b0 + r) * HP + cc * 8];
                }
                preA[i] = v;
            }
            #pragma unroll
            for (int i = 0; i < 6; i++) {
                int c = tid + i * 384;
                if (c < 2048) {
                    int r = c >> 6, cc = c & 63;
                    *(s16x8*)&sh[r * 520 + cc * 8] = preA[i];
                }
            }
        }
        __syncthreads();                                   // (a) SA ready

        // ---- layer 0 MFMA: t = s, h from SA (k split across parts)
        if (hasL0) {
            f32x4 a0 = {0.f,0.f,0.f,0.f}, a1 = {0.f,0.f,0.f,0.f};
            #pragma unroll
            for (int i = 0; i < 8; i++) {
                int kk = part * 8 + i;
                s16x8 x0 = *(const s16x8*)&sh[arow * 520 + kk * 32 + acol];
                s16x8 x1 = *(const s16x8*)&sh[(16 + arow) * 520 + kk * 32 + acol];
                a0 = __builtin_amdgcn_mfma_f32_16x16x32_bf16(x0, w0f[i], a0, 0, 0, 0);
                a1 = __builtin_amdgcn_mfma_f32_16x16x32_bf16(x1, w0f[i], a1, 0, 0, 0);
            }
            put_hg(a0, a1);
        }
        // ---- prefetch SC <- ysA[s-3] (BYPASS: lines were re-written by l2)
        s16x8 preC[6];
        {
            int tprev = s - 3;
            #pragma unroll
            for (int i = 0; i < 6; i++) {
                int c = tid + i * 384;
                s16x8 v = z8;
                if (hasL2 && c < 2048 && tprev >= 0) {
                    int r = c >> 6, cc = c & 63;
                    const ull* p = (const ull*)&ysA[((size_t)tprev * BATCH + b0 + r) * HP + cc * 8];
                    union { ull q[2]; s16x8 v; } uu;
                    uu.q[0] = __hip_atomic_load(p,     __ATOMIC_RELAXED, __HIP_MEMORY_SCOPE_AGENT);
                    uu.q[1] = __hip_atomic_load(p + 1, __ATOMIC_RELAXED, __HIP_MEMORY_SCOPE_AGENT);
                    v = uu.v;
                }
                preC[i] = v;
            }
        }
        __syncthreads();                                   // (b) hg0 ready

        // ---- layer 0 gate: out -> ysA[s] (sc1)
        if (hasL0) {
            short* dst = ysA + (size_t)s * BATCH * HP;
            for (int idx = tid; idx < 256; idx += 384) {
                int m = idx >> 3, pr = idx & 7, b = b0 + m;
                unsigned pk = 0;
                #pragma unroll
                for (int e = 0; e < 2; e++) {
                    int ul = pr * 2 + e, u = j * 16 + ul, mo = m * 17 + ul;
                    float hv = 0.f;
                    if (u < H) {
                        float hr = hg[0][mo] + hg[1][mo];
                        float hz = hg[2][mo] + hg[3][mo];
                        float hn = hg[4][mo] + hg[5][mo];
                        float r = sigm(sg0[m * 48 + ul] + hr);
                        float z = sigm(sg0[m * 48 + 16 + ul] + hz);
                        float n = tanh_fast(sg0[m * 48 + 32 + ul] + r * (hn + sb[0][3][ul]));
                        float hold = bf2f(sh[m * 520 + u]);
                        hv = (1.f - z) * n + z * hold;
                    }
                    pk |= ((unsigned)(unsigned short)f2bf(hv)) << (16 * e);
                }
                __hip_atomic_store((unsigned*)&dst[(size_t)b * HP + j * 16 + pr * 2], pk,
                                   __ATOMIC_RELAXED, __HIP_MEMORY_SCOPE_AGENT);
            }
        }
        __syncthreads();                                   // (c) gate0 done with hg/sh

        // ---- layer 1 MFMA: t = s-1; x from SA(LDS), h direct cached ysB[s-2]
        if (hasL1) {
            f32x4 a0 = {0.f,0.f,0.f,0.f}, a1 = {0.f,0.f,0.f,0.f};
            if (part == 0) {
                #pragma unroll
                for (int kk = 0; kk < 16; kk++) {
                    s16x8 x0 = *(const s16x8*)&sh[arow * 520 + kk * 32 + acol];
                    s16x8 x1 = *(const s16x8*)&sh[(16 + arow) * 520 + kk * 32 + acol];
                    a0 = __builtin_amdgcn_mfma_f32_16x16x32_bf16(x0, w1f[kk], a0, 0, 0, 0);
                    a1 = __builtin_amdgcn_mfma_f32_16x16x32_bf16(x1, w1f[kk], a1, 0, 0, 0);
                }
            } else if (s >= 2) {
                const short* hb = ysB + (size_t)(s - 2) * BATCH * HP;
                #pragma unroll
                for (int kk = 0; kk < 16; kk++) {
                    s16x8 h0 = *(const s16x8*)&hb[(size_t)(b0 + arow) * HP + kk * 32 + acol];
                    s16x8 h1 = *(const s16x8*)&hb[(size_t)(b0 + 16 + arow) * HP + kk * 32 + acol];
                    a0 = __builtin_amdgcn_mfma_f32_16x16x32_bf16(h0, w1f[kk], a0, 0, 0, 0);
                    a1 = __builtin_amdgcn_mfma_f32_16x16x32_bf16(h1, w1f[kk], a1, 0, 0, 0);
                }
            }
            put_hg(a0, a1);
        }
        __syncthreads();                                   // (d) hg1 ready, SA dead

        // ---- commit SC into sh (overwrites SA) + layer1 gate -> ysB[s-1]
        if (hasL2) {
            #pragma unroll
            for (int i = 0; i < 6; i++) {
                int c = tid + i * 384;
                if (c < 2048) {
                    int r = c >> 6, cc = c & 63;
                    *(s16x8*)&sh[r * 520 + cc * 8] = preC[i];
                }
            }
        }
        if (hasL1) {
            const short* holdsrc = (s >= 2) ? ysB + (size_t)(s - 2) * BATCH * HP : nullptr;
            short* dst = ysB + (size_t)(s - 1) * BATCH * HP;
            for (int idx = tid; idx < 256; idx += 384) {
                int m = idx >> 3, pr = idx & 7, b = b0 + m;
                unsigned pk = 0;
                #pragma unroll
                for (int e = 0; e < 2; e++) {
                    int ul = pr * 2 + e, u = j * 16 + ul, mo = m * 17 + ul;
                    float hv = 0.f;
                    if (u < H) {
                        float xr = hg[0][mo] + sb[1][0][ul];
                        float hr = hg[1][mo];
                        float xz = hg[2][mo] + sb[1][1][ul];
                        float hz = hg[3][mo];
                        float xn = hg[4][mo] + sb[1][2][ul];
                        float hn = hg[5][mo] + sb[1][3][ul];
                        float r = sigm(xr + hr);
                        float z = sigm(xz + hz);
                        float n = tanh_fast(xn + r * hn);
                        float hold = holdsrc ? bf2f(holdsrc[(size_t)b * HP + u]) : 0.f;
                        hv = (1.f - z) * n + z * hold;
                    }
                    pk |= ((unsigned)(unsigned short)f2bf(hv)) << (16 * e);
                }
                __hip_atomic_store((unsigned*)&dst[(size_t)b * HP + j * 16 + pr * 2], pk,
                                   __ATOMIC_RELAXED, __HIP_MEMORY_SCOPE_AGENT);
            }
        }
        __syncthreads();                                   // (e) SC ready, hg free

        // ---- layer 2 MFMA: t = s-2; x direct cached ysB[s-2] (L2-warm), h from SC(LDS)
        if (hasL2) {
            f32x4 a0 = {0.f,0.f,0.f,0.f}, a1 = {0.f,0.f,0.f,0.f};
            if (part == 0) {
                const short* xb = ysB + (size_t)(s - 2) * BATCH * HP;
                #pragma unroll
                for (int kk = 0; kk < 16; kk++) {
                    s16x8 x0 = *(const s16x8*)&xb[(size_t)(b0 + arow) * HP + kk * 32 + acol];
                    s16x8 x1 = *(const s16x8*)&xb[(size_t)(b0 + 16 + arow) * HP + kk * 32 + acol];
                    a0 = __builtin_amdgcn_mfma_f32_16x16x32_bf16(x0, w2f[kk], a0, 0, 0, 0);
                    a1 = __builtin_amdgcn_mfma_f32_16x16x32_bf16(x1, w2f[kk], a1, 0, 0, 0);
                }
            } else {
                #pragma unroll
                for (int kk = 0; kk < 16; kk++) {
                    s16x8 h0 = *(const s16x8*)&sh[arow * 520 + kk * 32 + acol];
                    s16x8 h1 = *(const s16x8*)&sh[(16 + arow) * 520 + kk * 32 + acol];
                    a0 = __builtin_amdgcn_mfma_f32_16x16x32_bf16(h0, w2f[kk], a0, 0, 0, 0);
                    a1 = __builtin_amdgcn_mfma_f32_16x16x32_bf16(h1, w2f[kk], a1, 0, 0, 0);
                }
            }
            put_hg(a0, a1);
        }
        __syncthreads();                                   // (f) hg2 ready

        // ---- layer 2 gate: out -> ysA[s-2] (sc1; final layer2 output for fc2)
        if (hasL2) {
            short* dst = ysA + (size_t)(s - 2) * BATCH * HP;
            for (int idx = tid; idx < 256; idx += 384) {
                int m = idx >> 3, pr = idx & 7, b = b0 + m;
                unsigned pk = 0;
                #pragma unroll
                for (int e = 0; e < 2; e++) {
                    int ul = pr * 2 + e, u = j * 16 + ul, mo = m * 17 + ul;
                    float hv = 0.f;
                    if (u < H) {
                        float xr = hg[0][mo] + sb[2][0][ul];
                        float hr = hg[1][mo];
                        float xz = hg[2][mo] + sb[2][1][ul];
                        float hz = hg[3][mo];
                        float xn = hg[4][mo] + sb[2][2][ul];
                        float hn = hg[5][mo] + sb[2][3][ul];
                        float r = sigm(xr + hr);
                        float z = sigm(xz + hz);
                        float n = tanh_fast(xn + r * hn);
                        float hold = bf2f(sh[m * 520 + u]);
                        hv = (1.f - z) * n + z * hold;
                    }
                    pk |= ((unsigned)(unsigned short)f2bf(hv)) << (16 * e);
                }
                __hip_atomic_store((unsigned*)&dst[(size_t)b * HP + j * 16 + pr * 2], pk,
                                   __ATOMIC_RELAXED, __HIP_MEMORY_SCOPE_AGENT);
            }
        }
        __syncthreads();    // (g) barrier drains all waves' vmcnt => sc1 stores at L3

        // ---- per-bg 32-block barrier: relaxed add + relaxed poll (no wbL2)
        if (tid == 0) {
            asm volatile("s_waitcnt vmcnt(0)" ::: "memory");
            __hip_atomic_fetch_add(mycnt, 1u, __ATOMIC_RELAXED, __HIP_MEMORY_SCOPE_AGENT);
            unsigned tgt = 32u * (unsigned)(s + 1);
            while (__hip_atomic_load(mycnt, __ATOMIC_RELAXED, __HIP_MEMORY_SCOPE_AGENT) < tgt) {}
        }
        __syncthreads();                                   // (h)
    }
}

// ---------------------------------------------------------------------------
// fc2 + transpose (reads ysA = layer2 output; fresh kernel => coherent)
// ---------------------------------------------------------------------------
__global__ __launch_bounds__(256, 1)
void k_fc2(const short* __restrict__ ys2, const short* __restrict__ fc2p,
           const float* __restrict__ fc2_b, float* __restrict__ out) {
    int b = blockIdx.x;
    int tid = threadIdx.x, lane = tid & 63, wave = tid >> 6;
    const s16x8 zf = {0, 0, 0, 0, 0, 0, 0, 0};
    for (int ntile = wave; ntile < 18; ntile += 4) {
        int tt = ntile * 16 + (lane & 15);
        s16x8 bf[16];
        for (int kt = 0; kt < 16; kt++) {
            if (tt < T_STEPS)
                bf[kt] = *(const s16x8*)&ys2[((size_t)tt * BATCH + b) * HP + kt * 32 + (lane >> 4) * 8];
            else
                bf[kt] = zf;
        }
        for (int mt = 0; mt < 5; mt++) {
            f32x4 acc = {0.f, 0.f, 0.f, 0.f};
            for (int kt = 0; kt < 16; kt++) {
                s16x8 af = *(const s16x8*)&fc2p[(((size_t)mt * 16 + kt) * 64 + lane) * 8];
                acc = __builtin_amdgcn_mfma_f32_16x16x32_bf16(af, bf[kt], acc, 0, 0, 0);
            }
            int obase = mt * 16 + (lane >> 4) * 4;
            for (int r = 0; r < 4; r++) {
                int o = obase + r;
                if (o < O_OUT && tt < T_STEPS)
                    out[((size_t)b * O_OUT + o) * T_STEPS + tt] = acc[r] + fc2_b[o];
            }
        }
    }
}

// ---------------------------------------------------------------------------
extern "C" void kernel_launch(void* const* d_in, const int* in_sizes, int n_in,
                              void* d_out, int out_size, void* d_ws, size_t ws_size,
                              hipStream_t stream) {
    const float* x     = (const float*)d_in[0];
    const float* fc1_w = (const float*)d_in[1];
    const float* fc1_b = (const float*)d_in[2];
    const float* w_ih0 = (const float*)d_in[3];
    const float* w_hh0 = (const float*)d_in[4];
    const float* b_ih0 = (const float*)d_in[5];
    const float* b_hh0 = (const float*)d_in[6];
    const float* w_ih1 = (const float*)d_in[7];
    const float* w_hh1 = (const float*)d_in[8];
    const float* b_ih1 = (const float*)d_in[9];
    const float* b_hh1 = (const float*)d_in[10];
    const float* w_ih2 = (const float*)d_in[11];
    const float* w_hh2 = (const float*)d_in[12];
    const float* b_ih2 = (const float*)d_in[13];
    const float* b_hh2 = (const float*)d_in[14];
    const float* fc2_w = (const float*)d_in[15];
    const float* fc2_b = (const float*)d_in[16];
    float* out = (float*)d_out;

    char* p = (char*)d_ws;
    auto alloc = [&](size_t bytes) {
        char* r = p; p += (bytes + 255) & ~(size_t)255; return r;
    };
    short* packW0 = (short*)alloc((size_t)32 * 3 * 16 * 64 * 8 * 2);
    short* packW1 = (short*)alloc((size_t)32 * 3 * 32 * 64 * 8 * 2);
    short* packW2 = (short*)alloc((size_t)32 * 3 * 32 * 64 * 8 * 2);
    short* packF  = (short*)alloc((size_t)80 * 64 * 8 * 2);
    float* hin    = (float*)alloc((size_t)BATCH * 64 * 4);
    float* g0     = (float*)alloc((size_t)BATCH * NP * 4);
    unsigned* cnt = (unsigned*)alloc(256 * 4);
    short* ysA    = (short*)alloc((size_t)T_STEPS * BATCH * HP * 2);
    short* ysB    = (short*)alloc((size_t)T_STEPS * BATCH * HP * 2);

    hipMemsetAsync(cnt, 0, 256 * 4, stream);
    k_pack_gru<<<32 * 3 * 16, 64, 0, stream>>>(nullptr, w_hh0, packW0, 16);
    k_pack_gru<<<32 * 3 * 32, 64, 0, stream>>>(w_ih1, w_hh1, packW1, 32);
    k_pack_gru<<<32 * 3 * 32, 64, 0, stream>>>(w_ih2, w_hh2, packW2, 32);
    k_pack_fc2<<<80, 64, 0, stream>>>(fc2_w, packF);
    k_hin<<<BATCH, 64, 0, stream>>>(x, fc1_w, fc1_b, hin);
    k_g0<<<BATCH, 256, 0, stream>>>(hin, w_ih0, b_ih0, g0);

    k_gru_persist<<<256, 384, 0, stream>>>(packW0, packW1, packW2, g0,
                                           b_hh0, b_ih1, b_hh1, b_ih2, b_hh2,
                                           ysA, ysB, cnt);

    k_fc2<<<BATCH, 256, 0, stream>>>(ysA, packF, fc2_b, out);
}